// Round 3
// baseline (123.159 us; speedup 1.0000x reference)
//
#include <hip/hip_runtime.h>

// FeatureShader: pytorch3d softmax_rgb_blend + TexturesVertex barycentric gather.
// N,H,W,K,C = 4,256,256,8,16.
//
// R3 layout: one thread per (pixel, channel-pair). Lane c of an 8-lane group
// also owns slot k=c for the coalesced z/d/p2f loads (addr == thread id).
// Softmax max/denom: 6 shfl_xor. Active slots iterated from a ballot mask
// (~1.4/group): per trip 2 bpermutes (w, f) + group-uniform bary/faces loads
// + one float2 vfeat gather per vertex per lane (8 lanes = one 64B line).
// No 16-channel reduce-scatter -> ds-op count per wave ~12 (was ~20).

constexpr int KK = 8;

__global__ __launch_bounds__(256) void feature_shader_r3(
    const float* __restrict__ dists,
    const float* __restrict__ zbuf,
    const float* __restrict__ bary,
    const float* __restrict__ vfeat,
    const float* __restrict__ bg,
    const int*   __restrict__ p2f,
    const int*   __restrict__ faces,
    float* __restrict__ out,
    int n)   // n = N*H*W*K = 2097152
{
    const float INV_SIGMA = 1e4f;          // 1/SIGMA
    const float INV_GAMMA = 1e4f;          // 1/GAMMA
    const float EPS       = 1e-10f;
    const float ZFAR      = 100.f;
    const float INV_SPAN  = 1.f / 99.f;    // 1/(ZFAR-ZNEAR)

    int t = blockIdx.x * blockDim.x + threadIdx.x;
    if (t >= n) return;
    int lane = threadIdx.x & 63;
    int c    = lane & (KK - 1);            // channel-pair AND slot index
    int base = lane & ~(KK - 1);           // wave-relative group base
    int p    = t >> 3;                     // pixel

    // Coalesced per-slot loads (address == t).
    float z  = zbuf[t];
    float dd = dists[t];
    int   f  = p2f[t];

    float zinv = (f >= 0) ? (ZFAR - z) * INV_SPAN : 0.f;

    // Group max (8-lane butterfly) then clip.
    float m = zinv;
    m = fmaxf(m, __shfl_xor(m, 1));
    m = fmaxf(m, __shfl_xor(m, 2));
    m = fmaxf(m, __shfl_xor(m, 4));
    m = fmaxf(m, EPS);

    float delta = fmaxf(__expf((EPS - m) * INV_GAMMA), EPS);
    float prob  = (f >= 0) ? 1.f / (1.f + __expf(dd * INV_SIGMA)) : 0.f;
    float w     = prob * __expf((zinv - m) * INV_GAMMA);

    // Group sum -> denominator (uniform across the group).
    float denom = w;
    denom += __shfl_xor(denom, 1);
    denom += __shfl_xor(denom, 2);
    denom += __shfl_xor(denom, 4);
    denom += delta;
    float thr = denom * 1e-7f;   // skip gather below this; abs err ~1e-6

    // Per-group active-slot mask from the wave-wide ballot.
    unsigned long long bal = __ballot(w > thr);
    unsigned gmask = (unsigned)((bal >> base) & 0xFFull);

    float accx = 0.f, accy = 0.f;

    // Iterate active slots (group-uniform loop, ~1.4 trips avg).
    while (gmask) {
        int j = __builtin_ctz(gmask);
        gmask &= gmask - 1;

        float wj = __shfl(w, base | j);
        int   fj = __shfl(f, base | j);

        // Group-uniform loads: one line each via L1/L2 broadcast.
        const float* bp = bary + (size_t)(p * KK + j) * 3;
        float b0 = bp[0] * wj, b1 = bp[1] * wj, b2 = bp[2] * wj;
        int v0 = faces[fj * 3 + 0];
        int v1 = faces[fj * 3 + 1];
        int v2 = faces[fj * 3 + 2];

        // Each lane gathers its 8B channel-pair; group covers one 64B line/vertex.
        float2 a0 = ((const float2*)(vfeat + (size_t)v0 * 16))[c];
        float2 a1 = ((const float2*)(vfeat + (size_t)v1 * 16))[c];
        float2 a2 = ((const float2*)(vfeat + (size_t)v2 * 16))[c];

        accx += b0 * a0.x + b1 * a1.x + b2 * a2.x;
        accy += b0 * a0.y + b1 * a1.y + b2 * a2.y;
    }

    float2 g = ((const float2*)bg)[c];
    float inv_den = 1.f / denom;
    float2 o;
    o.x = (accx + delta * g.x) * inv_den;
    o.y = (accy + delta * g.y) * inv_den;
    ((float2*)out)[t] = o;    // out[p*16 + 2c .. 2c+1], fully coalesced
}

extern "C" void kernel_launch(void* const* d_in, const int* in_sizes, int n_in,
                              void* d_out, int out_size, void* d_ws, size_t ws_size,
                              hipStream_t stream) {
    const float* dists = (const float*)d_in[0];
    const float* zbuf  = (const float*)d_in[1];
    const float* bary  = (const float*)d_in[2];
    const float* vfeat = (const float*)d_in[3];
    const float* bg    = (const float*)d_in[4];
    const int*   p2f   = (const int*)d_in[5];
    const int*   faces = (const int*)d_in[6];
    float* out = (float*)d_out;

    int n = in_sizes[0];                   // N*H*W*K = 2097152
    int block = 256;
    int grid = (n + block - 1) / block;    // 8192 blocks

    hipLaunchKernelGGL(feature_shader_r3, dim3(grid), dim3(block), 0, stream,
                       dists, zbuf, bary, vfeat, bg, p2f, faces, out, n);
}